// Round 1
// baseline (12389.674 us; speedup 1.0000x reference)
//
#include <hip/hip_runtime.h>
#include <stdint.h>

typedef __attribute__((ext_vector_type(8))) short bf16x8;
typedef __attribute__((ext_vector_type(4))) float f32x4;
typedef unsigned short u16;

#define MFMA16(a, b, c) __builtin_amdgcn_mfma_f32_16x16x32_bf16((a), (b), (c), 0, 0, 0)

static constexpr int T_STEPS = 256;
static constexpr int BATCH   = 2048;
static constexpr int YDIM    = 20;
static constexpr int BS      = 16;            // batch rows per WG
static constexpr int NWG     = BATCH / BS;    // 128

// ws layout (u16 elements)
static constexpr int O_WHH0  = 0;             // [768][256]
static constexpr int O_WIH1  = 196608;        // [768][256]
static constexpr int O_WHH1  = 393216;        // [768][256]
static constexpr int O_W1    = 589824;        // [256][256]
static constexpr int O_W2    = 655360;        // [256][256]
static constexpr int O_W3P   = 720896;        // [32][256] zero-padded rows >= 20
static constexpr int O_WIH0P = 729088;        // [768][32] zero-padded cols >= 20
static constexpr int WS_TOTAL= 753664;

__device__ __forceinline__ u16 f2bf(float x) {
    uint32_t u = __float_as_uint(x);
    u += 0x7FFFu + ((u >> 16) & 1u);
    return (u16)(u >> 16);
}
__device__ __forceinline__ float bf2f(u16 h) {
    return __uint_as_float(((uint32_t)h) << 16);
}
__device__ __forceinline__ float sigm(float x) { return 1.0f / (1.0f + __expf(-x)); }
__device__ __forceinline__ float tanh_fast(float x) {
    float s = __expf(-2.0f * fabsf(x));
    float r = (1.0f - s) / (1.0f + s);
    return copysignf(r, x);
}
__device__ __forceinline__ f32x4 zero4() { f32x4 v = {0.f, 0.f, 0.f, 0.f}; return v; }

__global__ void prep_kernel(const float* __restrict__ Wih0, const float* __restrict__ Whh0,
                            const float* __restrict__ Wih1, const float* __restrict__ Whh1,
                            const float* __restrict__ W1,   const float* __restrict__ W2,
                            const float* __restrict__ W3,   u16* __restrict__ ws,
                            float* __restrict__ out) {
    int tid = blockIdx.x * blockDim.x + threadIdx.x;
    if (tid == 0) out[0] = 0.0f;
    int stride = gridDim.x * blockDim.x;
    for (int i = tid; i < WS_TOTAL; i += stride) {
        float v;
        if (i < O_WIH1)       v = Whh0[i];
        else if (i < O_WHH1)  v = Wih1[i - O_WIH1];
        else if (i < O_W1)    v = Whh1[i - O_WHH1];
        else if (i < O_W2)    v = W1[i - O_W1];
        else if (i < O_W3P)   v = W2[i - O_W2];
        else if (i < O_WIH0P) { int j = i - O_W3P;  int o = j >> 8; int k = j & 255;
                                v = (o < YDIM) ? W3[o * 256 + k] : 0.0f; }
        else                  { int j = i - O_WIH0P; int o = j >> 5; int c = j & 31;
                                v = (c < YDIM) ? Wih0[o * YDIM + c] : 0.0f; }
        ws[i] = f2bf(v);
    }
}

__global__ __launch_bounds__(256) void rnn_main(
    const float* __restrict__ data,
    const float* __restrict__ bih0, const float* __restrict__ bhh0,
    const float* __restrict__ bih1, const float* __restrict__ bhh1,
    const float* __restrict__ b1g,  const float* __restrict__ b2g,
    const float* __restrict__ b3g,
    const u16* __restrict__ ws, float* __restrict__ out)
{
    // LDS. Row stride 264 (528 B): 16B-aligned rows, 2-way-max bank aliasing (free).
    __shared__ u16 sh_h0[16][264];
    __shared__ u16 sh_h1[16][264];
    __shared__ u16 sh_d1[16][264];
    __shared__ u16 sh_d2[16][264];
    __shared__ u16 sh_x[16][40];   // x_t padded to 32 cols (cols 20..31 stay 0)
    __shared__ float sbih0[768], sbhh0[768], sbih1[768], sbhh1[768];
    __shared__ float sb1[256], sb2[256], sb3[32];

    const int tid  = threadIdx.x;
    const int wv   = tid >> 6;       // wave 0..3
    const int lane = tid & 63;
    const int l16  = lane & 15;
    const int kq   = lane >> 4;      // quarter-wave 0..3
    const int b0   = blockIdx.x * BS;
    const int aoff = kq * 8;         // k-offset within fragment row

    const u16* __restrict__ whh0  = ws + O_WHH0;
    const u16* __restrict__ wih1  = ws + O_WIH1;
    const u16* __restrict__ whh1  = ws + O_WHH1;
    const u16* __restrict__ w1    = ws + O_W1;
    const u16* __restrict__ w2    = ws + O_W2;
    const u16* __restrict__ w3p   = ws + O_W3P;
    const u16* __restrict__ wih0p = ws + O_WIH0P;

    for (int i = tid; i < 16 * 264; i += 256) { (&sh_h0[0][0])[i] = 0; (&sh_h1[0][0])[i] = 0; }
    for (int i = tid; i < 16 * 40;  i += 256) (&sh_x[0][0])[i] = 0;
    for (int i = tid; i < 768; i += 256) {
        sbih0[i] = bih0[i]; sbhh0[i] = bhh0[i];
        sbih1[i] = bih1[i]; sbhh1[i] = bhh1[i];
    }
    sb1[tid] = b1g[tid]; sb2[tid] = b2g[tid];
    if (tid < 32) sb3[tid] = (tid < YDIM) ? b3g[tid] : 0.0f;
    __syncthreads();

    float loss = 0.0f;

    for (int t = 0; t < T_STEPS - 1; ++t) {
        // ---- P0: stage x_t into LDS (bf16, zero-padded) ----
        {
            const float* xp = data + (size_t)t * (BATCH * YDIM) + (size_t)b0 * YDIM;
            for (int i = tid; i < BS * YDIM; i += 256) {
                int r = i / YDIM, c = i - r * YDIM;
                sh_x[r][c] = f2bf(xp[i]);
            }
        }
        __syncthreads();

        // ---- P1: gh0 (12 tiles over 768 gate-cols) + gx0 merged ----
        // wave wv owns tiles t = g*16 + wv + 4*jj : matching (r,z,n) gate triples.
        f32x4 acc[12], accxn[4];
        #pragma unroll
        for (int j = 0; j < 12; ++j) acc[j] = zero4();
        #pragma unroll
        for (int j = 0; j < 4; ++j) accxn[j] = zero4();

        #pragma unroll 2
        for (int kb = 0; kb < 8; ++kb) {
            const bf16x8 a = *(const bf16x8*)&sh_h0[l16][kb * 32 + aoff];
            #pragma unroll
            for (int j = 0; j < 12; ++j) {
                const int tl = (j >> 2) * 16 + wv + 4 * (j & 3);
                const bf16x8 b = *(const bf16x8*)(whh0 + (size_t)(tl * 16 + l16) * 256 + kb * 32 + aoff);
                acc[j] = MFMA16(a, b, acc[j]);  // gh0
            }
        }
        {   // gx0: K padded 20->32, single MFMA per tile. Merge into acc for r,z; separate for n.
            const bf16x8 ax = *(const bf16x8*)&sh_x[l16][aoff];
            #pragma unroll
            for (int j = 0; j < 12; ++j) {
                const int tl = (j >> 2) * 16 + wv + 4 * (j & 3);
                const bf16x8 b = *(const bf16x8*)(wih0p + (size_t)(tl * 16 + l16) * 32 + aoff);
                if (j < 8) acc[j] = MFMA16(ax, b, acc[j]);
                else       accxn[j - 8] = MFMA16(ax, b, accxn[j - 8]);  // gx0_n
            }
        }
        __syncthreads();

        // ---- P3: GRU combine layer 0 -> sh_h0 (acc[8+jj]=gh0_n, accxn[jj]=gx0_n) ----
        #pragma unroll
        for (int jj = 0; jj < 4; ++jj) {
            const int colb = (wv + 4 * jj) * 16 + l16;
            const float biR = sbih0[colb] + sbhh0[colb];
            const float biZ = sbih0[colb + 256] + sbhh0[colb + 256];
            const float bxN = sbih0[colb + 512];
            const float bhN = sbhh0[colb + 512];
            #pragma unroll
            for (int q = 0; q < 4; ++q) {
                const int row = kq * 4 + q;
                const float r = sigm(acc[jj][q] + biR);
                const float z = sigm(acc[4 + jj][q] + biZ);
                const float n = tanh_fast(accxn[jj][q] + bxN + r * (acc[8 + jj][q] + bhN));
                const float hp = bf2f(sh_h0[row][colb]);
                sh_h0[row][colb] = f2bf((1.0f - z) * n + z * hp);
            }
        }
        __syncthreads();

        // ---- P5: gx1 + gh1 ----
        #pragma unroll
        for (int j = 0; j < 12; ++j) acc[j] = zero4();
        #pragma unroll
        for (int j = 0; j < 4; ++j) accxn[j] = zero4();
        #pragma unroll 2
        for (int kb = 0; kb < 8; ++kb) {
            const bf16x8 a0 = *(const bf16x8*)&sh_h0[l16][kb * 32 + aoff];
            const bf16x8 a1 = *(const bf16x8*)&sh_h1[l16][kb * 32 + aoff];
            #pragma unroll
            for (int j = 0; j < 12; ++j) {
                const int tl = (j >> 2) * 16 + wv + 4 * (j & 3);
                const size_t ro = (size_t)(tl * 16 + l16) * 256 + kb * 32 + aoff;
                const bf16x8 bx = *(const bf16x8*)(wih1 + ro);
                acc[j] = MFMA16(a0, bx, acc[j]);                    // gx1
                const bf16x8 bh = *(const bf16x8*)(whh1 + ro);
                if (j < 8) acc[j] = MFMA16(a1, bh, acc[j]);         // + gh1 (r,z)
                else       accxn[j - 8] = MFMA16(a1, bh, accxn[j - 8]);  // gh1_n
            }
        }
        __syncthreads();

        // ---- P6: GRU combine layer 1 -> sh_h1 (acc[8+jj]=gx1_n, accxn[jj]=gh1_n) ----
        #pragma unroll
        for (int jj = 0; jj < 4; ++jj) {
            const int colb = (wv + 4 * jj) * 16 + l16;
            const float biR = sbih1[colb] + sbhh1[colb];
            const float biZ = sbih1[colb + 256] + sbhh1[colb + 256];
            const float bxN = sbih1[colb + 512];
            const float bhN = sbhh1[colb + 512];
            #pragma unroll
            for (int q = 0; q < 4; ++q) {
                const int row = kq * 4 + q;
                const float r = sigm(acc[jj][q] + biR);
                const float z = sigm(acc[4 + jj][q] + biZ);
                const float n = tanh_fast(acc[8 + jj][q] + bxN + r * (accxn[jj][q] + bhN));
                const float hp = bf2f(sh_h1[row][colb]);
                sh_h1[row][colb] = f2bf((1.0f - z) * n + z * hp);
            }
        }
        __syncthreads();

        // ---- P8: d1 = relu(h1 @ W1^T + b1) ----
        {
            f32x4 dacc[4];
            #pragma unroll
            for (int i = 0; i < 4; ++i) dacc[i] = zero4();
            #pragma unroll 2
            for (int kb = 0; kb < 8; ++kb) {
                const bf16x8 a = *(const bf16x8*)&sh_h1[l16][kb * 32 + aoff];
                #pragma unroll
                for (int i = 0; i < 4; ++i) {
                    const int tl = wv * 4 + i;
                    const bf16x8 b = *(const bf16x8*)(w1 + (size_t)(tl * 16 + l16) * 256 + kb * 32 + aoff);
                    dacc[i] = MFMA16(a, b, dacc[i]);
                }
            }
            #pragma unroll
            for (int i = 0; i < 4; ++i) {
                const int col = (wv * 4 + i) * 16 + l16;
                #pragma unroll
                for (int q = 0; q < 4; ++q)
                    sh_d1[kq * 4 + q][col] = f2bf(fmaxf(dacc[i][q] + sb1[col], 0.0f));
            }
        }
        __syncthreads();

        // ---- P10: d2 = relu(d1 @ W2^T + b2) ----
        {
            f32x4 dacc[4];
            #pragma unroll
            for (int i = 0; i < 4; ++i) dacc[i] = zero4();
            #pragma unroll 2
            for (int kb = 0; kb < 8; ++kb) {
                const bf16x8 a = *(const bf16x8*)&sh_d1[l16][kb * 32 + aoff];
                #pragma unroll
                for (int i = 0; i < 4; ++i) {
                    const int tl = wv * 4 + i;
                    const bf16x8 b = *(const bf16x8*)(w2 + (size_t)(tl * 16 + l16) * 256 + kb * 32 + aoff);
                    dacc[i] = MFMA16(a, b, dacc[i]);
                }
            }
            #pragma unroll
            for (int i = 0; i < 4; ++i) {
                const int col = (wv * 4 + i) * 16 + l16;
                #pragma unroll
                for (int q = 0; q < 4; ++q)
                    sh_d2[kq * 4 + q][col] = f2bf(fmaxf(dacc[i][q] + sb2[col], 0.0f));
            }
        }
        __syncthreads();

        // ---- P12: d3 = d2 @ W3^T + b3; loss vs data[t+1] (waves 0,1 only) ----
        if (wv < 2) {
            f32x4 lacc = zero4();
            #pragma unroll 2
            for (int kb = 0; kb < 8; ++kb) {
                const bf16x8 a = *(const bf16x8*)&sh_d2[l16][kb * 32 + aoff];
                const bf16x8 b = *(const bf16x8*)(w3p + (size_t)(wv * 16 + l16) * 256 + kb * 32 + aoff);
                lacc = MFMA16(a, b, lacc);
            }
            const int col = wv * 16 + l16;
            if (col < YDIM) {
                const float* tp = data + (size_t)(t + 1) * (BATCH * YDIM) + (size_t)b0 * YDIM;
                #pragma unroll
                for (int q = 0; q < 4; ++q) {
                    const int row = kq * 4 + q;
                    const float d = (lacc[q] + sb3[col]) - tp[row * YDIM + col];
                    loss += d * d;
                }
            }
        }
        // no barrier needed: next P0 writes sh_x (all P1 readers are past P2 of this step)
    }

    // final reduction: wave shuffle -> one atomic per wave
    #pragma unroll
    for (int s = 32; s > 0; s >>= 1) loss += __shfl_down(loss, s, 64);
    if (lane == 0) atomicAdd(out, loss);
}

extern "C" void kernel_launch(void* const* d_in, const int* in_sizes, int n_in,
                              void* d_out, int out_size, void* d_ws, size_t ws_size,
                              hipStream_t stream) {
    const float* data = (const float*)d_in[0];
    const float* Wih0 = (const float*)d_in[1];
    const float* Whh0 = (const float*)d_in[2];
    const float* bih0 = (const float*)d_in[3];
    const float* bhh0 = (const float*)d_in[4];
    const float* Wih1 = (const float*)d_in[5];
    const float* Whh1 = (const float*)d_in[6];
    const float* bih1 = (const float*)d_in[7];
    const float* bhh1 = (const float*)d_in[8];
    const float* W1   = (const float*)d_in[9];
    const float* b1   = (const float*)d_in[10];
    const float* W2   = (const float*)d_in[11];
    const float* b2   = (const float*)d_in[12];
    const float* W3   = (const float*)d_in[13];
    const float* b3   = (const float*)d_in[14];
    u16*   ws  = (u16*)d_ws;
    float* out = (float*)d_out;

    hipLaunchKernelGGL(prep_kernel, dim3(512), dim3(256), 0, stream,
                       Wih0, Whh0, Wih1, Whh1, W1, W2, W3, ws, out);
    hipLaunchKernelGGL(rnn_main, dim3(NWG), dim3(256), 0, stream,
                       data, bih0, bhh0, bih1, bhh1, b1, b2, b3, ws, out);
}

// Round 2
// 5597.736 us; speedup vs baseline: 2.2133x; 2.2133x over previous
//
#include <hip/hip_runtime.h>
#include <stdint.h>

typedef __attribute__((ext_vector_type(8))) short bf16x8;
typedef __attribute__((ext_vector_type(4))) float f32x4;
typedef unsigned short u16;

#define MFMA16(a, b, c) __builtin_amdgcn_mfma_f32_16x16x32_bf16((a), (b), (c), 0, 0, 0)

static constexpr int T_STEPS = 256;
static constexpr int BATCH   = 2048;
static constexpr int YDIM    = 20;
static constexpr int BS      = 16;            // batch rows per WG
static constexpr int NWG     = BATCH / BS;    // 128

// fragment-linear ws layout (u16 elements).
// A "block" = 1 KB = 512 u16: lane L (0..63) holds 8 u16 at L*8:
//   W[row = tl*16 + (L&15)][col = kb*32 + (L>>4)*8 + j]
static constexpr int CH48     = 24576;        // 48 KB chunk (48 blocks)
static constexpr int CH16     = 8192;         // 16 KB chunk (16 blocks)
static constexpr int OFF_WHH0 = 0;                    // 8 chunks (kb)
static constexpr int OFF_WIH0 = 8 * CH48;             // 196608, 1 chunk (K padded 20->32)
static constexpr int OFF_L1   = OFF_WIH0 + CH48;      // 221184, per kb: [whh1_kb][wih1_kb]
static constexpr int OFF_W1   = OFF_L1 + 16 * CH48;   // 614400, 8 chunks (kb), 16 blocks each
static constexpr int OFF_W2   = OFF_W1 + 8 * CH16;    // 679936
static constexpr int OFF_W3   = OFF_W2 + 8 * CH16;    // 745472, 1 chunk: block = kb*2 + tl
static constexpr int WS_TOTAL = OFF_W3 + CH16;        // 753664 u16 = 1.44 MB

__device__ __forceinline__ u16 f2bf(float x) {
    uint32_t u = __float_as_uint(x);
    u += 0x7FFFu + ((u >> 16) & 1u);
    return (u16)(u >> 16);
}
__device__ __forceinline__ float bf2f(u16 h) {
    return __uint_as_float(((uint32_t)h) << 16);
}
__device__ __forceinline__ float sigm(float x) { return 1.0f / (1.0f + __expf(-x)); }
__device__ __forceinline__ float tanh_fast(float x) {
    float s = __expf(-2.0f * fabsf(x));
    float r = (1.0f - s) / (1.0f + s);
    return copysignf(r, x);
}
__device__ __forceinline__ f32x4 zero4() { f32x4 v = {0.f, 0.f, 0.f, 0.f}; return v; }

// ---- prep: convert + permute weights into fragment-linear chunk layout ----
__global__ void prep_kernel(const float* __restrict__ Wih0, const float* __restrict__ Whh0,
                            const float* __restrict__ Wih1, const float* __restrict__ Whh1,
                            const float* __restrict__ W1,   const float* __restrict__ W2,
                            const float* __restrict__ W3,   u16* __restrict__ ws,
                            float* __restrict__ out) {
    int tid = blockIdx.x * blockDim.x + threadIdx.x;
    if (tid == 0) out[0] = 0.0f;
    int stride = gridDim.x * blockDim.x;
    for (int i = tid; i < WS_TOTAL; i += stride) {
        float v;
        if (i < OFF_WIH0) {                           // whh0 kb-chunks
            int kb = i / CH48, rr = i % CH48;
            int tl = rr >> 9, q = rr & 511, lane = q >> 3, j = q & 7;
            int row = tl * 16 + (lane & 15), col = kb * 32 + (lane >> 4) * 8 + j;
            v = Whh0[row * 256 + col];
        } else if (i < OFF_L1) {                      // wih0 padded K=32
            int rr = i - OFF_WIH0;
            int tl = rr >> 9, q = rr & 511, lane = q >> 3, j = q & 7;
            int row = tl * 16 + (lane & 15), col = (lane >> 4) * 8 + j;
            v = (col < YDIM) ? Wih0[row * YDIM + col] : 0.0f;
        } else if (i < OFF_W1) {                      // [whh1_kb][wih1_kb] pairs
            int rel = i - OFF_L1;
            int kb = rel / (2 * CH48), sub = rel % (2 * CH48);
            int mat = sub / CH48, rr = sub % CH48;
            int tl = rr >> 9, q = rr & 511, lane = q >> 3, j = q & 7;
            int row = tl * 16 + (lane & 15), col = kb * 32 + (lane >> 4) * 8 + j;
            v = (mat == 0) ? Whh1[row * 256 + col] : Wih1[row * 256 + col];
        } else if (i < OFF_W2) {                      // w1 kb-chunks
            int rel = i - OFF_W1;
            int kb = rel / CH16, rr = rel % CH16;
            int tl = rr >> 9, q = rr & 511, lane = q >> 3, j = q & 7;
            int row = tl * 16 + (lane & 15), col = kb * 32 + (lane >> 4) * 8 + j;
            v = W1[row * 256 + col];
        } else if (i < OFF_W3) {                      // w2 kb-chunks
            int rel = i - OFF_W2;
            int kb = rel / CH16, rr = rel % CH16;
            int tl = rr >> 9, q = rr & 511, lane = q >> 3, j = q & 7;
            int row = tl * 16 + (lane & 15), col = kb * 32 + (lane >> 4) * 8 + j;
            v = W2[row * 256 + col];
        } else {                                      // w3 padded rows, block = kb*2+tl
            int rr = i - OFF_W3;
            int blk = rr >> 9, q = rr & 511, lane = q >> 3, j = q & 7;
            int kb = blk >> 1, tl = blk & 1;
            int row = tl * 16 + (lane & 15), col = kb * 32 + (lane >> 4) * 8 + j;
            v = (row < YDIM) ? W3[row * 256 + col] : 0.0f;
        }
        ws[i] = f2bf(v);
    }
}

__global__ __launch_bounds__(512) void rnn_main(
    const float* __restrict__ data,
    const float* __restrict__ bih0g, const float* __restrict__ bhh0g,
    const float* __restrict__ bih1g, const float* __restrict__ bhh1g,
    const float* __restrict__ b1g,  const float* __restrict__ b2g,
    const float* __restrict__ b3g,
    const u16* __restrict__ ws, float* __restrict__ out)
{
    __shared__ u16 sh_h0[16][264];
    __shared__ u16 sh_h1[16][264];
    __shared__ u16 sh_d1[16][264];
    __shared__ u16 sh_d2[16][264];
    __shared__ u16 sh_x[16][40];
    __shared__ float sbih0[768], sbhh0[768], sbih1[768], sbhh1[768];
    __shared__ float sb1[256], sb2[256], sb3[32];
    __shared__ u16 wbuf[2][CH48];     // 96 KB double buffer

    const int tid  = threadIdx.x;
    const int w    = tid >> 6;        // wave 0..7
    const int lane = tid & 63;
    const int l16  = lane & 15;
    const int kq   = lane >> 4;
    const int aoff = kq * 8;
    const int b0   = blockIdx.x * BS;

    for (int i = tid; i < 16 * 264; i += 512) { (&sh_h0[0][0])[i] = 0; (&sh_h1[0][0])[i] = 0; }
    for (int i = tid; i < 16 * 40;  i += 512) (&sh_x[0][0])[i] = 0;
    for (int i = tid; i < 768; i += 512) {
        sbih0[i] = bih0g[i]; sbhh0[i] = bhh0g[i];
        sbih1[i] = bih1g[i]; sbhh1[i] = bhh1g[i];
    }
    if (tid < 256) { sb1[tid] = b1g[tid]; sb2[tid] = b2g[tid]; }
    if (tid < 32)  sb3[tid] = (tid < YDIM) ? b3g[tid] : 0.0f;

    // issue one chunk into wbuf[buf]: nloads per thread, each = 64 lanes x 16 B block
    auto issue = [&](int buf, const u16* src, int nloads) {
        #pragma unroll
        for (int i = 0; i < nloads; ++i) {
            const int blk = i * 8 + w;
            __builtin_amdgcn_global_load_lds(
                (const __attribute__((address_space(1))) void*)(src + (size_t)blk * 512 + lane * 8),
                (__attribute__((address_space(3))) void*)(&wbuf[buf][blk * 512]),
                16, 0, 0);
        }
    };

    f32x4 aR[2], aZ[2], aXN[2], aHN[2];
    auto zeroAcc = [&]() {
        #pragma unroll
        for (int jj = 0; jj < 2; ++jj) { aR[jj] = zero4(); aZ[jj] = zero4(); aXN[jj] = zero4(); aHN[jj] = zero4(); }
    };
    // 3 gates x 2 col-subtiles from wbuf[buf]; mode 0: g2->aHN, mode 1: g2->aXN
    auto mm3 = [&](int buf, bf16x8 a, int mode) {
        #pragma unroll
        for (int g = 0; g < 3; ++g)
            #pragma unroll
            for (int jj = 0; jj < 2; ++jj) {
                const int blk = g * 16 + w + 8 * jj;
                const bf16x8 b = *(const bf16x8*)&wbuf[buf][blk * 512 + lane * 8];
                if (g == 0)      aR[jj] = MFMA16(a, b, aR[jj]);
                else if (g == 1) aZ[jj] = MFMA16(a, b, aZ[jj]);
                else if (mode)   aXN[jj] = MFMA16(a, b, aXN[jj]);
                else             aHN[jj] = MFMA16(a, b, aHN[jj]);
            }
    };
    auto combine = [&](u16 (*H)[264], const float* bi, const float* bh) {
        #pragma unroll
        for (int jj = 0; jj < 2; ++jj) {
            const int colb = (w + 8 * jj) * 16 + l16;
            const float biR = bi[colb] + bh[colb];
            const float biZ = bi[colb + 256] + bh[colb + 256];
            const float bxN = bi[colb + 512];
            const float bhN = bh[colb + 512];
            #pragma unroll
            for (int q = 0; q < 4; ++q) {
                const int row = kq * 4 + q;
                const float r = sigm(aR[jj][q] + biR);
                const float z = sigm(aZ[jj][q] + biZ);
                const float n = tanh_fast(aXN[jj][q] + bxN + r * (aHN[jj][q] + bhN));
                const float hp = bf2f(H[row][colb]);
                H[row][colb] = f2bf((1.0f - z) * n + z * hp);
            }
        }
    };

    // prologue: chunk c0 (whh0 kb0) -> buf0
    issue(0, ws + OFF_WHH0, 6);
    __syncthreads();

    float loss = 0.0f;

    #pragma unroll 1
    for (int t = 0; t < T_STEPS - 1; ++t) {
        // ---- c0..c7: gh0 (A = sh_h0 old) ----
        #pragma unroll 1
        for (int kb = 0; kb < 8; ++kb) {
            const int pc = kb & 1;
            issue(pc ^ 1, kb < 7 ? ws + OFF_WHH0 + (size_t)(kb + 1) * CH48 : ws + OFF_WIH0, 6);
            if (kb == 0) {
                const float* xp = data + (size_t)t * (BATCH * YDIM) + (size_t)b0 * YDIM;
                if (tid < BS * YDIM) sh_x[tid / YDIM][tid % YDIM] = f2bf(xp[tid]);
                zeroAcc();
            }
            const bf16x8 a = *(const bf16x8*)&sh_h0[l16][kb * 32 + aoff];
            mm3(pc, a, 0);
            __syncthreads();
        }
        // ---- c8: gx0 (A = sh_x), then fused combine0 -> sh_h0 ----
        issue(1, ws + OFF_L1, 6);   // whh1 kb0 -> c9
        {
            const bf16x8 ax = *(const bf16x8*)&sh_x[l16][aoff];
            mm3(0, ax, 1);
        }
        combine(sh_h0, sbih0, sbhh0);
        __syncthreads();
        // ---- c9..c24: per kb: [gh1 (A=sh_h1 old)] [gx1 (A=sh_h0 new)]; combine1 fused at end ----
        #pragma unroll 1
        for (int kb = 0; kb < 8; ++kb) {
            issue(0, ws + OFF_L1 + (size_t)kb * 2 * CH48 + CH48, 6);   // wih1 kb
            if (kb == 0) zeroAcc();
            { const bf16x8 a = *(const bf16x8*)&sh_h1[l16][kb * 32 + aoff]; mm3(1, a, 0); }
            __syncthreads();
            issue(1, kb < 7 ? ws + OFF_L1 + (size_t)(kb + 1) * 2 * CH48 : ws + OFF_W1,
                  kb < 7 ? 6 : 2);
            { const bf16x8 a = *(const bf16x8*)&sh_h0[l16][kb * 32 + aoff]; mm3(0, a, 1); }
            if (kb == 7) combine(sh_h1, sbih1, sbhh1);
            __syncthreads();
        }
        // ---- c25..c32: d1 = relu(h1 @ W1^T + b1), ACT fused at kb=7 ----
        f32x4 dacc0, dacc1;
        #pragma unroll 1
        for (int kb = 0; kb < 8; ++kb) {
            const int pc = (kb + 1) & 1;    // c25 -> buf1
            issue(pc ^ 1, kb < 7 ? ws + OFF_W1 + (size_t)(kb + 1) * CH16 : ws + OFF_W2, 2);
            if (kb == 0) { dacc0 = zero4(); dacc1 = zero4(); }
            const bf16x8 a = *(const bf16x8*)&sh_h1[l16][kb * 32 + aoff];
            {
                const bf16x8 bb0 = *(const bf16x8*)&wbuf[pc][(w) * 512 + lane * 8];
                dacc0 = MFMA16(a, bb0, dacc0);
                const bf16x8 bb1 = *(const bf16x8*)&wbuf[pc][(w + 8) * 512 + lane * 8];
                dacc1 = MFMA16(a, bb1, dacc1);
            }
            if (kb == 7) {
                #pragma unroll
                for (int jj = 0; jj < 2; ++jj) {
                    const int col = (w + 8 * jj) * 16 + l16;
                    const f32x4 dd = jj ? dacc1 : dacc0;
                    #pragma unroll
                    for (int q = 0; q < 4; ++q)
                        sh_d1[kq * 4 + q][col] = f2bf(fmaxf(dd[q] + sb1[col], 0.0f));
                }
            }
            __syncthreads();
        }
        // ---- c33..c40: d2 = relu(d1 @ W2^T + b2), ACT fused at kb=7 ----
        #pragma unroll 1
        for (int kb = 0; kb < 8; ++kb) {
            const int pc = (kb + 1) & 1;    // c33 -> buf1
            issue(pc ^ 1, kb < 7 ? ws + OFF_W2 + (size_t)(kb + 1) * CH16 : ws + OFF_W3, 2);
            if (kb == 0) { dacc0 = zero4(); dacc1 = zero4(); }
            const bf16x8 a = *(const bf16x8*)&sh_d1[l16][kb * 32 + aoff];
            {
                const bf16x8 bb0 = *(const bf16x8*)&wbuf[pc][(w) * 512 + lane * 8];
                dacc0 = MFMA16(a, bb0, dacc0);
                const bf16x8 bb1 = *(const bf16x8*)&wbuf[pc][(w + 8) * 512 + lane * 8];
                dacc1 = MFMA16(a, bb1, dacc1);
            }
            if (kb == 7) {
                #pragma unroll
                for (int jj = 0; jj < 2; ++jj) {
                    const int col = (w + 8 * jj) * 16 + l16;
                    const f32x4 dd = jj ? dacc1 : dacc0;
                    #pragma unroll
                    for (int q = 0; q < 4; ++q)
                        sh_d2[kq * 4 + q][col] = f2bf(fmaxf(dd[q] + sb2[col], 0.0f));
                }
            }
            __syncthreads();
        }
        // ---- c41: d3 + loss (waves 0,1); prefetch next step's c0 ----
        issue(0, ws + OFF_WHH0, 6);
        if (w < 2) {
            f32x4 lacc = zero4();
            #pragma unroll
            for (int kb = 0; kb < 8; ++kb) {
                const bf16x8 a = *(const bf16x8*)&sh_d2[l16][kb * 32 + aoff];
                const bf16x8 b = *(const bf16x8*)&wbuf[1][(kb * 2 + w) * 512 + lane * 8];
                lacc = MFMA16(a, b, lacc);
            }
            const int col = w * 16 + l16;
            if (col < YDIM) {
                const float* tp = data + (size_t)(t + 1) * (BATCH * YDIM) + (size_t)b0 * YDIM;
                #pragma unroll
                for (int q = 0; q < 4; ++q) {
                    const int row = kq * 4 + q;
                    const float d = (lacc[q] + sb3[col]) - tp[row * YDIM + col];
                    loss += d * d;
                }
            }
        }
        __syncthreads();
    }

    #pragma unroll
    for (int s = 32; s > 0; s >>= 1) loss += __shfl_down(loss, s, 64);
    if (lane == 0) atomicAdd(out, loss);
}

extern "C" void kernel_launch(void* const* d_in, const int* in_sizes, int n_in,
                              void* d_out, int out_size, void* d_ws, size_t ws_size,
                              hipStream_t stream) {
    const float* data = (const float*)d_in[0];
    const float* Wih0 = (const float*)d_in[1];
    const float* Whh0 = (const float*)d_in[2];
    const float* bih0 = (const float*)d_in[3];
    const float* bhh0 = (const float*)d_in[4];
    const float* Wih1 = (const float*)d_in[5];
    const float* Whh1 = (const float*)d_in[6];
    const float* bih1 = (const float*)d_in[7];
    const float* bhh1 = (const float*)d_in[8];
    const float* W1   = (const float*)d_in[9];
    const float* b1   = (const float*)d_in[10];
    const float* W2   = (const float*)d_in[11];
    const float* b2   = (const float*)d_in[12];
    const float* W3   = (const float*)d_in[13];
    const float* b3   = (const float*)d_in[14];
    u16*   ws  = (u16*)d_ws;
    float* out = (float*)d_out;

    hipLaunchKernelGGL(prep_kernel, dim3(512), dim3(256), 0, stream,
                       Wih0, Whh0, Wih1, Whh1, W1, W2, W3, ws, out);
    hipLaunchKernelGGL(rnn_main, dim3(NWG), dim3(512), 0, stream,
                       data, bih0, bhh0, bih1, bhh1, b1, b2, b3, ws, out);
}

// Round 3
// 4874.481 us; speedup vs baseline: 2.5417x; 1.1484x over previous
//
#include <hip/hip_runtime.h>
#include <stdint.h>

typedef __attribute__((ext_vector_type(8))) short bf16x8;
typedef __attribute__((ext_vector_type(4))) float f32x4;
typedef unsigned short u16;

#define MFMA16(a,b,c) __builtin_amdgcn_mfma_f32_16x16x32_bf16((a),(b),(c),0,0,0)

static constexpr int T_STEPS = 256;
static constexpr int BATCH   = 2048;
static constexpr int YDIM    = 20;
static constexpr int BS      = 16;            // batch rows per WG
static constexpr int NWG     = BATCH / BS;    // 128

// ws: 1504 blocks of 1KB (512 u16), laid out in EXACT stream/consumption order.
// Block b, lane L (0..63), j (0..7): element = W[row][k] with row = rowbase + (L&15),
// k = kb*32 + (L>>4)*8 + j.
// [0,384):    whh0, kb-major (48 blocks per kb: g*16+c)
// [384,432):  wih0, K padded 20->32 (48 blocks)
// [432,448):  zero pad
// [448,1216): L1: per kb {whh1 48 | wih1 48}
// [1216,1344): W1 (per kb 16 blocks)
// [1344,1472): W2
// [1472,1488): W3 (rows padded 20->32)
// [1488,1504): zero pad
static constexpr int NBLK     = 1504;
static constexpr int NCHUNK   = 47;           // 32-block chunks per step
static constexpr int CHUNK_U16= 32 * 512;     // 16384 u16 = 32 KB
static constexpr int WS_TOTAL = NBLK * 512;   // 770048 u16

__device__ __forceinline__ u16 f2bf(float x) {
    uint32_t u = __float_as_uint(x);
    u += 0x7FFFu + ((u >> 16) & 1u);
    return (u16)(u >> 16);
}
__device__ __forceinline__ float bf2f(u16 h) {
    return __uint_as_float(((uint32_t)h) << 16);
}
__device__ __forceinline__ float sigm(float x) { return 1.0f / (1.0f + __expf(-x)); }
__device__ __forceinline__ float tanh_fast(float x) {
    float s = __expf(-2.0f * fabsf(x));
    float r = (1.0f - s) / (1.0f + s);
    return copysignf(r, x);
}
__device__ __forceinline__ f32x4 zero4() { f32x4 v = {0.f, 0.f, 0.f, 0.f}; return v; }

__global__ void prep_kernel(const float* __restrict__ Wih0, const float* __restrict__ Whh0,
                            const float* __restrict__ Wih1, const float* __restrict__ Whh1,
                            const float* __restrict__ W1,   const float* __restrict__ W2,
                            const float* __restrict__ W3,   u16* __restrict__ ws,
                            float* __restrict__ out) {
    int tid = blockIdx.x * blockDim.x + threadIdx.x;
    if (tid == 0) out[0] = 0.0f;
    int stride = gridDim.x * blockDim.x;
    for (int i = tid; i < WS_TOTAL; i += stride) {
        int b = i >> 9, q = i & 511, lane = q >> 3, j = q & 7;
        int r = lane & 15, k8 = (lane >> 4) * 8 + j;   // k within 32-col kb
        float v = 0.0f;
        if (b < 384) {
            int kb = b / 48, r48 = b % 48;
            int row = r48 * 16 + r, col = kb * 32 + k8;
            v = Whh0[row * 256 + col];
        } else if (b < 432) {
            int r48 = b - 384;
            int row = r48 * 16 + r;
            v = (k8 < YDIM) ? Wih0[row * YDIM + k8] : 0.0f;
        } else if (b < 448) {
            v = 0.0f;
        } else if (b < 1216) {
            int rel = b - 448;
            int kb = rel / 96, sub = rel % 96;
            int h = sub / 48, r48 = sub % 48;
            int row = r48 * 16 + r, col = kb * 32 + k8;
            v = (h == 0) ? Whh1[row * 256 + col] : Wih1[row * 256 + col];
        } else if (b < 1344) {
            int rel = b - 1216;
            int kb = rel / 16, c = rel % 16;
            int row = c * 16 + r, col = kb * 32 + k8;
            v = W1[row * 256 + col];
        } else if (b < 1472) {
            int rel = b - 1344;
            int kb = rel / 16, c = rel % 16;
            int row = c * 16 + r, col = kb * 32 + k8;
            v = W2[row * 256 + col];
        } else if (b < 1488) {
            int rel = b - 1472;
            int kb = rel / 2, c = rel % 2;
            int row = c * 16 + r, col = kb * 32 + k8;
            v = (row < YDIM) ? W3[row * 256 + col] : 0.0f;
        }
        ws[i] = f2bf(v);
    }
}

__global__ __launch_bounds__(512, 1) void rnn_main(
    const float* __restrict__ data,
    const float* __restrict__ bih0g, const float* __restrict__ bhh0g,
    const float* __restrict__ bih1g, const float* __restrict__ bhh1g,
    const float* __restrict__ b1g,  const float* __restrict__ b2g,
    const float* __restrict__ b3g,
    const u16* __restrict__ ws, float* __restrict__ out)
{
    __shared__ u16 wbuf[4][CHUNK_U16];   // 128 KB chunk ring
    __shared__ u16 sh_h0[16][264];       // recurrent state, persists across steps
    __shared__ u16 sh_h1[16][264];
    __shared__ u16 sh_d[16][264];        // d1 then d2 (aliased, extra barrier)
    __shared__ u16 sh_x[16][40];         // x_t, K padded to 32 (cols>=20 zero)

    const int tid  = threadIdx.x;
    const int w    = tid >> 6;           // wave 0..7
    const int lane = tid & 63;
    const int l16  = lane & 15;
    const int kq   = lane >> 4;
    const int aoff = kq * 8;
    const int b0   = blockIdx.x * BS;

    // ---- init LDS ----
    for (int i = tid; i < 16 * 264; i += 512) { (&sh_h0[0][0])[i] = 0; (&sh_h1[0][0])[i] = 0; }
    for (int i = tid; i < 16 * 40;  i += 512) (&sh_x[0][0])[i] = 0;
    // stage x(0)
    if (tid < BS * YDIM) sh_x[tid / YDIM][tid % YDIM] = f2bf(data[b0 * YDIM + tid]);

    // ---- biases to registers ----
    float bR0[2], bZ0[2], bXN0[2], bHN0[2];
    float bR1[2], bZ1[2], bXN1[2], bHN1[2];
    float s1r[2], s2r[2];
    #pragma unroll
    for (int jj = 0; jj < 2; ++jj) {
        const int colb = (w + 8 * jj) * 16 + l16;
        bR0[jj]  = bih0g[colb] + bhh0g[colb];
        bZ0[jj]  = bih0g[colb + 256] + bhh0g[colb + 256];
        bXN0[jj] = bih0g[colb + 512];
        bHN0[jj] = bhh0g[colb + 512];
        bR1[jj]  = bih1g[colb] + bhh1g[colb];
        bZ1[jj]  = bih1g[colb + 256] + bhh1g[colb + 256];
        bXN1[jj] = bih1g[colb + 512];
        bHN1[jj] = bhh1g[colb + 512];
        s1r[jj]  = b1g[colb];
        s2r[jj]  = b2g[colb];
    }
    float s3r = 0.0f;
    { const int col = w * 16 + l16; if (w < 2 && col < YDIM) s3r = b3g[col]; }

    // ---- chunk pipeline state ----
    int issPtr = 0;    // next chunk index (0..46) to issue
    int issBuf = 0;    // LDS ring slot for next issue
    int curBuf = 3;    // slot of chunk about to be computed (after first CTOP -> 0)

    auto issueOne = [&]() {
        const u16* src = ws + (size_t)issPtr * CHUNK_U16;
        #pragma unroll
        for (int i = 0; i < 4; ++i) {
            const int blk = i * 8 + w;
            __builtin_amdgcn_global_load_lds(
                (const __attribute__((address_space(1))) void*)(src + blk * 512 + lane * 8),
                (__attribute__((address_space(3))) void*)(&wbuf[issBuf][blk * 512]),
                16, 0, 0);
        }
        issPtr = (issPtr == NCHUNK - 1) ? 0 : issPtr + 1;
        issBuf = (issBuf + 1) & 3;
    };
    // chunk top: issue 2-ahead, wait for CURRENT chunk only (8 newer loads stay in flight)
    auto CTOP = [&]() {
        issueOne();
        asm volatile("s_waitcnt vmcnt(8) lgkmcnt(0)" ::: "memory");
        __builtin_amdgcn_sched_barrier(0);
        __builtin_amdgcn_s_barrier();
        __builtin_amdgcn_sched_barrier(0);
        curBuf = (curBuf + 1) & 3;
    };

    // B fragment from current chunk
    auto BR = [&](int local) {
        return *(const bf16x8*)&wbuf[curBuf][local * 512 + lane * 8];
    };
    auto AH = [&](u16 (*S)[264], int kb) {
        return *(const bf16x8*)&S[l16][kb * 32 + aoff];
    };

    f32x4 aR[2], aZ[2], aXN[2], aHN[2];
    auto zeroAcc = [&]() {
        #pragma unroll
        for (int jj = 0; jj < 2; ++jj) { aR[jj] = zero4(); aZ[jj] = zero4(); aXN[jj] = zero4(); aHN[jj] = zero4(); }
    };
    auto combine = [&](u16 (*H)[264], const float* cbR, const float* cbZ,
                       const float* cbXN, const float* cbHN) {
        #pragma unroll
        for (int jj = 0; jj < 2; ++jj) {
            const int colb = (w + 8 * jj) * 16 + l16;
            #pragma unroll
            for (int q = 0; q < 4; ++q) {
                const int row = kq * 4 + q;
                const float r = sigm(aR[jj][q] + cbR[jj]);
                const float z = sigm(aZ[jj][q] + cbZ[jj]);
                const float n = tanh_fast(aXN[jj][q] + cbXN[jj] + r * (aHN[jj][q] + cbHN[jj]));
                const float hp = bf2f(H[row][colb]);
                H[row][colb] = f2bf((1.0f - z) * n + z * hp);
            }
        }
    };

    // prologue: issue chunks 0,1 (no waits)
    issueOne();
    issueOne();

    float loss = 0.0f;

    #pragma unroll 1
    for (int t = 0; t < T_STEPS - 1; ++t) {
        // ======== gh0: whh0 kb 0..7, chunks 0..11 ========
        zeroAcc();
        #pragma unroll 1
        for (int m = 0; m < 4; ++m) {           // kb pair (2m, 2m+1)
            CTOP();                              // chunk 3m
            {
                const bf16x8 a = AH(sh_h0, 2 * m);
                aR[0] = MFMA16(a, BR(w),      aR[0]);  aR[1] = MFMA16(a, BR(8 + w),  aR[1]);
                aZ[0] = MFMA16(a, BR(16 + w), aZ[0]);  aZ[1] = MFMA16(a, BR(24 + w), aZ[1]);
            }
            CTOP();                              // chunk 3m+1
            {
                const bf16x8 a  = AH(sh_h0, 2 * m);
                aHN[0] = MFMA16(a, BR(w),      aHN[0]); aHN[1] = MFMA16(a, BR(8 + w),  aHN[1]);
                const bf16x8 a2 = AH(sh_h0, 2 * m + 1);
                aR[0]  = MFMA16(a2, BR(16 + w), aR[0]); aR[1]  = MFMA16(a2, BR(24 + w), aR[1]);
            }
            CTOP();                              // chunk 3m+2
            {
                const bf16x8 a2 = AH(sh_h0, 2 * m + 1);
                aZ[0]  = MFMA16(a2, BR(w),      aZ[0]);  aZ[1]  = MFMA16(a2, BR(8 + w),  aZ[1]);
                aHN[0] = MFMA16(a2, BR(16 + w), aHN[0]); aHN[1] = MFMA16(a2, BR(24 + w), aHN[1]);
            }
        }
        // ======== gx0: wih0, chunks 12,13; then combine0 -> sh_h0 ========
        {
            const bf16x8 ax = *(const bf16x8*)&sh_x[l16][aoff];
            CTOP();                              // chunk 12
            aR[0] = MFMA16(ax, BR(w),      aR[0]);  aR[1] = MFMA16(ax, BR(8 + w),  aR[1]);
            aZ[0] = MFMA16(ax, BR(16 + w), aZ[0]);  aZ[1] = MFMA16(ax, BR(24 + w), aZ[1]);
            CTOP();                              // chunk 13 (upper half = pad)
            aXN[0] = MFMA16(ax, BR(w), aXN[0]);  aXN[1] = MFMA16(ax, BR(8 + w), aXN[1]);
        }
        combine(sh_h0, bR0, bZ0, bXN0, bHN0);
        // ======== L1: per kb {whh1 | wih1}, chunks 14..37; combine1 -> sh_h1 ========
        zeroAcc();
        #pragma unroll 1
        for (int j = 0; j < 8; ++j) {
            CTOP();                              // chunk 14+3j
            {
                const bf16x8 a1 = AH(sh_h1, j);
                aR[0] = MFMA16(a1, BR(w),      aR[0]);  aR[1] = MFMA16(a1, BR(8 + w),  aR[1]);
                aZ[0] = MFMA16(a1, BR(16 + w), aZ[0]);  aZ[1] = MFMA16(a1, BR(24 + w), aZ[1]);
            }
            CTOP();                              // chunk 15+3j
            {
                const bf16x8 a1 = AH(sh_h1, j);
                aHN[0] = MFMA16(a1, BR(w),     aHN[0]); aHN[1] = MFMA16(a1, BR(8 + w), aHN[1]);
                const bf16x8 a0 = AH(sh_h0, j);
                aR[0]  = MFMA16(a0, BR(16 + w), aR[0]); aR[1]  = MFMA16(a0, BR(24 + w), aR[1]);
            }
            CTOP();                              // chunk 16+3j
            {
                const bf16x8 a0 = AH(sh_h0, j);
                aZ[0]  = MFMA16(a0, BR(w),      aZ[0]);  aZ[1]  = MFMA16(a0, BR(8 + w),  aZ[1]);
                aXN[0] = MFMA16(a0, BR(16 + w), aXN[0]); aXN[1] = MFMA16(a0, BR(24 + w), aXN[1]);
            }
        }
        combine(sh_h1, bR1, bZ1, bXN1, bHN1);
        // ======== W1: chunks 38..41 -> d1 (relu) -> sh_d ========
        {
            f32x4 d0 = zero4(), d1v = zero4();
            #pragma unroll 1
            for (int kb = 0; kb < 8; ++kb) {
                if ((kb & 1) == 0) CTOP();       // chunks 38..41
                if (kb == 0 && t < T_STEPS - 2 && tid < BS * YDIM) {
                    const float* xp = data + (size_t)(t + 1) * (BATCH * YDIM) + (size_t)b0 * YDIM;
                    sh_x[tid / YDIM][tid % YDIM] = f2bf(xp[tid]);
                }
                const bf16x8 a = AH(sh_h1, kb);
                d0  = MFMA16(a, BR((kb & 1) * 16 + w),     d0);
                d1v = MFMA16(a, BR((kb & 1) * 16 + 8 + w), d1v);
            }
            #pragma unroll
            for (int jj = 0; jj < 2; ++jj) {
                const int col = (w + 8 * jj) * 16 + l16;
                const f32x4 dd = jj ? d1v : d0;
                #pragma unroll
                for (int q = 0; q < 4; ++q)
                    sh_d[kq * 4 + q][col] = f2bf(fmaxf(dd[q] + s1r[jj], 0.0f));
            }
        }
        // ======== W2: chunks 42..45 -> d2 (relu) -> sh_d (aliased) ========
        {
            f32x4 d0 = zero4(), d1v = zero4();
            #pragma unroll 1
            for (int kb = 0; kb < 8; ++kb) {
                if ((kb & 1) == 0) CTOP();       // chunks 42..45 (lgkm orders d1 writes)
                const bf16x8 a = AH(sh_d, kb);
                d0  = MFMA16(a, BR((kb & 1) * 16 + w),     d0);
                d1v = MFMA16(a, BR((kb & 1) * 16 + 8 + w), d1v);
            }
            // all waves done reading d1 before overwriting with d2
            asm volatile("s_waitcnt lgkmcnt(0)" ::: "memory");
            __builtin_amdgcn_sched_barrier(0);
            __builtin_amdgcn_s_barrier();
            __builtin_amdgcn_sched_barrier(0);
            #pragma unroll
            for (int jj = 0; jj < 2; ++jj) {
                const int col = (w + 8 * jj) * 16 + l16;
                const f32x4 dd = jj ? d1v : d0;
                #pragma unroll
                for (int q = 0; q < 4; ++q)
                    sh_d[kq * 4 + q][col] = f2bf(fmaxf(dd[q] + s2r[jj], 0.0f));
            }
        }
        // ======== W3 + loss: chunk 46 ========
        CTOP();                                  // chunk 46 (lgkm orders d2 writes)
        if (w < 2) {
            f32x4 lacc = zero4();
            #pragma unroll
            for (int kb = 0; kb < 8; ++kb) {
                const bf16x8 a = AH(sh_d, kb);
                lacc = MFMA16(a, BR(kb * 2 + w), lacc);
            }
            const int col = w * 16 + l16;
            if (col < YDIM) {
                const float* tp = data + (size_t)(t + 1) * (BATCH * YDIM) + (size_t)b0 * YDIM;
                #pragma unroll
                for (int q = 0; q < 4; ++q) {
                    const int row = kq * 4 + q;
                    const float d = (lacc[q] + s3r) - tp[row * YDIM + col];
                    loss += d * d;
                }
            }
        }
    }

    #pragma unroll
    for (int s = 32; s > 0; s >>= 1) loss += __shfl_down(loss, s, 64);
    if (lane == 0) atomicAdd(out, loss);
}

extern "C" void kernel_launch(void* const* d_in, const int* in_sizes, int n_in,
                              void* d_out, int out_size, void* d_ws, size_t ws_size,
                              hipStream_t stream) {
    const float* data = (const float*)d_in[0];
    const float* Wih0 = (const float*)d_in[1];
    const float* Whh0 = (const float*)d_in[2];
    const float* bih0 = (const float*)d_in[3];
    const float* bhh0 = (const float*)d_in[4];
    const float* Wih1 = (const float*)d_in[5];
    const float* Whh1 = (const float*)d_in[6];
    const float* bih1 = (const float*)d_in[7];
    const float* bhh1 = (const float*)d_in[8];
    const float* W1   = (const float*)d_in[9];
    const float* b1   = (const float*)d_in[10];
    const float* W2   = (const float*)d_in[11];
    const float* b2   = (const float*)d_in[12];
    const float* W3   = (const float*)d_in[13];
    const float* b3   = (const float*)d_in[14];
    u16*   ws  = (u16*)d_ws;
    float* out = (float*)d_out;

    hipLaunchKernelGGL(prep_kernel, dim3(512), dim3(256), 0, stream,
                       Wih0, Whh0, Wih1, Whh1, W1, W2, W3, ws, out);
    hipLaunchKernelGGL(rnn_main, dim3(NWG), dim3(512), 0, stream,
                       data, bih0, bhh0, bih1, bhh1, b1, b2, b3, ws, out);
}